// Round 1
// 3220.112 us; speedup vs baseline: 1.2966x; 1.2966x over previous
//
#include <hip/hip_runtime.h>
#include <hip/hip_bf16.h>

typedef __hip_bfloat16 bf16;
typedef unsigned short u16;
typedef short short8 __attribute__((ext_vector_type(8)));
typedef float f32x4  __attribute__((ext_vector_type(4)));

static __device__ __forceinline__ float b2f(u16 u) {
    union { unsigned int i; float f; } c; c.i = (unsigned int)u << 16; return c.f;
}
static __device__ __forceinline__ u16 f2b(float f) {
    return (u16)__bfloat16_as_ushort(__float2bfloat16(f));
}

// Runtime-dtype load/store: flag==1 -> bf16, 0 -> fp32.
static __device__ __forceinline__ float ldf(const void* p, size_t i, int isbf16) {
    return isbf16 ? __bfloat162float(((const bf16*)p)[i]) : ((const float*)p)[i];
}
static __device__ __forceinline__ void stf(void* p, size_t i, float v, int isbf16) {
    if (isbf16) ((bf16*)p)[i] = __float2bfloat16(v);
    else        ((float*)p)[i] = v;
}

static __device__ __forceinline__ void async_copy16(const void* g, void* l) {
    __builtin_amdgcn_global_load_lds((const __attribute__((address_space(1))) void*)g,
                                     (__attribute__((address_space(3))) void*)l, 16, 0, 0);
}

// ---------------------------------------------------------------------------
// dtype detection (verbatim from passing version)
// ---------------------------------------------------------------------------
__global__ void detect_dtype(const unsigned short* __restrict__ x, int n, int* __restrict__ flag)
{
    __shared__ int cnt;
    if (threadIdx.x == 0) cnt = 0;
    __syncthreads();
    int local = 0;
    for (int i = threadIdx.x; i < n; i += blockDim.x) {
        const unsigned int e = (x[i] >> 7) & 0xFF;
        if (e >= 134u) local++;
    }
    atomicAdd(&cnt, local);
    __syncthreads();
    if (threadIdx.x == 0) *flag = (cnt >= 32) ? 0 : 1;
}

// ---------------------------------------------------------------------------
// SCALAR FALLBACK PATH (flag == 0) — round-2 kernels, now gated.
// ---------------------------------------------------------------------------
__global__ __launch_bounds__(256)
void gemm_bias(const void* __restrict__ A, int a_follows_flag,
               const void* __restrict__ W, const void* __restrict__ bias,
               void* __restrict__ C, int c_follows_flag,
               int M, int N, int K, const int* __restrict__ flagp)
{
    const int f = *flagp;
    if (f != 0) return;                 // bf16 runs use the MFMA path
    const int BM = 128, BN = 128, BK = 16;
    __shared__ float As[BK][BM + 4];
    __shared__ float Bs[BK][BN + 4];

    const int a_bf = a_follows_flag & f;
    const int c_bf = c_follows_flag & f;

    const int bm = blockIdx.y * BM;
    const int bn = blockIdx.x * BN;
    const int t  = threadIdx.x;
    const int tx = t & 15;
    const int ty = t >> 4;
    const int lrow = t >> 1;
    const int lcol = (t & 1) * 8;

    float acc[8][8];
#pragma unroll
    for (int i = 0; i < 8; i++)
#pragma unroll
        for (int j = 0; j < 8; j++) acc[i][j] = 0.f;

    for (int k0 = 0; k0 < K; k0 += BK) {
        __syncthreads();
        const size_t aoff = (size_t)(bm + lrow) * K + k0 + lcol;
        const size_t woff = (size_t)(bn + lrow) * K + k0 + lcol;
#pragma unroll
        for (int j = 0; j < 8; j++) As[lcol + j][lrow] = ldf(A, aoff + j, a_bf);
#pragma unroll
        for (int j = 0; j < 8; j++) Bs[lcol + j][lrow] = ldf(W, woff + j, f);
        __syncthreads();
#pragma unroll
        for (int kk = 0; kk < BK; kk++) {
            float a[8], b[8];
#pragma unroll
            for (int i = 0; i < 8; i++) a[i] = As[kk][ty * 8 + i];
#pragma unroll
            for (int j = 0; j < 8; j++) b[j] = Bs[kk][tx * 8 + j];
#pragma unroll
            for (int i = 0; i < 8; i++)
#pragma unroll
                for (int j = 0; j < 8; j++) acc[i][j] += a[i] * b[j];
        }
    }

#pragma unroll
    for (int i = 0; i < 8; i++) {
        const size_t row = (size_t)(bm + ty * 8 + i) * N + bn;
#pragma unroll
        for (int j = 0; j < 8; j++) {
            const float bj = ldf(bias, bn + tx * 8 + j, f);
            stf(C, row + tx * 8 + j, acc[i][j] + bj, c_bf);
        }
    }
}

__global__ __launch_bounds__(64)
void norm_rope(float* __restrict__ buf, const void* __restrict__ gain,
               int nheads, float scale, const int* __restrict__ flagp)
{
    if (*flagp != 0) return;
    const int id = blockIdx.x;
    const int h  = id % nheads;
    const int bs = id / nheads;
    const int s  = bs & 2047;
    float* v = buf + (size_t)bs * nheads * 128 + h * 128;
    const int i = threadIdx.x;

    float t1 = v[i];
    float t2 = v[i + 64];
    float ss = t1 * t1 + t2 * t2;
#pragma unroll
    for (int off = 32; off >= 1; off >>= 1) ss += __shfl_xor(ss, off);
    const float r = rsqrtf(ss * (1.0f / 128.0f) + 1.1920929e-07f);
    t1 *= r; t2 *= r;

    const float inv_freq = exp2f(-(float)i * 0.20762050593046014f);
    const float ph = (float)s * inv_freq;
    float sn, cs;
    __sincosf(ph, &sn, &cs);

    float g = scale;
    if (gain) g *= ldf(gain, h, 0);

    v[i]      = (t1 * cs + t2 * sn) * g;
    v[i + 64] = (-t1 * sn + t2 * cs) * g;
}

__global__ __launch_bounds__(256)
void attn_kernel(const float* __restrict__ Q, const float* __restrict__ K,
                 const float* __restrict__ V, float* __restrict__ Ctx,
                 const int* __restrict__ flagp)
{
    if (*flagp != 0) return;
    const int S = 2048, D = 2048, KVD = 512;
    __shared__ float Qs[32][132];
    __shared__ float Ks[32][132];
    __shared__ float Vs[32][132];
    __shared__ float Ps[32][33];

    const int q0 = blockIdx.x * 32;
    const int h  = blockIdx.y;
    const int b  = blockIdx.z;
    const int kvh = h >> 2;

    const float* Qbase = Q + (size_t)b * S * D + (size_t)h * 128;
    const float* Kbase = K + (size_t)b * S * KVD + (size_t)kvh * 128;
    const float* Vbase = V + (size_t)b * S * KVD + (size_t)kvh * 128;

    const int t  = threadIdx.x;
    const int tx = t & 15;
    const int ty = t >> 4;

    {
        const int row = t >> 3;
        const int col = (t & 7) * 16;
        const float* src = Qbase + (size_t)(q0 + row) * D + col;
#pragma unroll
        for (int j = 0; j < 16; j += 4)
            *(float4*)&Qs[row][col + j] = *(const float4*)&src[j];
    }

    float Oacc[2][8];
#pragma unroll
    for (int i = 0; i < 2; i++)
#pragma unroll
        for (int j = 0; j < 8; j++) Oacc[i][j] = 0.f;
    float m_i[2] = {-1e30f, -1e30f};
    float l_i[2] = {0.f, 0.f};

    const int ntiles = q0 / 32 + 1;
    for (int kt = 0; kt < ntiles; kt++) {
        const int k0 = kt * 32;
        __syncthreads();
        {
            const int row = t >> 3;
            const int col = (t & 7) * 16;
            const float* ksrc = Kbase + (size_t)(k0 + row) * KVD + col;
            const float* vsrc = Vbase + (size_t)(k0 + row) * KVD + col;
#pragma unroll
            for (int j = 0; j < 16; j += 4) {
                *(float4*)&Ks[row][col + j] = *(const float4*)&ksrc[j];
                *(float4*)&Vs[row][col + j] = *(const float4*)&vsrc[j];
            }
        }
        __syncthreads();

        float sc[2][2];
#pragma unroll
        for (int i = 0; i < 2; i++) { sc[i][0] = 0.f; sc[i][1] = 0.f; }
        for (int kk = 0; kk < 128; kk += 4) {
            float4 b0 = *(const float4*)&Ks[tx * 2 + 0][kk];
            float4 b1 = *(const float4*)&Ks[tx * 2 + 1][kk];
#pragma unroll
            for (int i = 0; i < 2; i++) {
                float4 a = *(const float4*)&Qs[ty * 2 + i][kk];
                sc[i][0] += a.x * b0.x + a.y * b0.y + a.z * b0.z + a.w * b0.w;
                sc[i][1] += a.x * b1.x + a.y * b1.y + a.z * b1.z + a.w * b1.w;
            }
        }

#pragma unroll
        for (int i = 0; i < 2; i++) {
            const int qg = q0 + ty * 2 + i;
            float mt = -1e30f;
#pragma unroll
            for (int j = 0; j < 2; j++) {
                if (k0 + tx * 2 + j > qg) sc[i][j] = -1e30f;
                mt = fmaxf(mt, sc[i][j]);
            }
#pragma unroll
            for (int off = 1; off < 16; off <<= 1) mt = fmaxf(mt, __shfl_xor(mt, off));
            const float mnew  = fmaxf(m_i[i], mt);
            const float alpha = __expf(m_i[i] - mnew);
            float psum = 0.f;
#pragma unroll
            for (int j = 0; j < 2; j++) {
                const float p = (sc[i][j] <= -1e29f) ? 0.f : __expf(sc[i][j] - mnew);
                Ps[ty * 2 + i][tx * 2 + j] = p;
                psum += p;
            }
#pragma unroll
            for (int off = 1; off < 16; off <<= 1) psum += __shfl_xor(psum, off);
            l_i[i] = l_i[i] * alpha + psum;
            m_i[i] = mnew;
#pragma unroll
            for (int j = 0; j < 8; j++) Oacc[i][j] *= alpha;
        }
        __syncthreads();

        for (int k = 0; k < 32; k++) {
            float4 v0 = *(const float4*)&Vs[k][tx * 8];
            float4 v1 = *(const float4*)&Vs[k][tx * 8 + 4];
#pragma unroll
            for (int i = 0; i < 2; i++) {
                const float p = Ps[ty * 2 + i][k];
                Oacc[i][0] += p * v0.x; Oacc[i][1] += p * v0.y;
                Oacc[i][2] += p * v0.z; Oacc[i][3] += p * v0.w;
                Oacc[i][4] += p * v1.x; Oacc[i][5] += p * v1.y;
                Oacc[i][6] += p * v1.z; Oacc[i][7] += p * v1.w;
            }
        }
    }

#pragma unroll
    for (int i = 0; i < 2; i++) {
        const float inv = 1.0f / l_i[i];
        float* dst = Ctx + (size_t)(b * S + q0 + ty * 2 + i) * D + h * 128 + tx * 8;
        float4 r0 = {Oacc[i][0] * inv, Oacc[i][1] * inv, Oacc[i][2] * inv, Oacc[i][3] * inv};
        float4 r1 = {Oacc[i][4] * inv, Oacc[i][5] * inv, Oacc[i][6] * inv, Oacc[i][7] * inv};
        *(float4*)&dst[0] = r0;
        *(float4*)&dst[4] = r1;
    }
}

// ---------------------------------------------------------------------------
// FAST PATH (flag == 1): bf16 MFMA everywhere.
// ---------------------------------------------------------------------------
// m97-structure MFMA GEMM: C[m][n] = sum_k A[m][k] * W[n][k]  (+ bias)
// obf:  output bf16 (else fp32).   brow: bias indexed by row (for V^T gemm).
__global__ __launch_bounds__(256)
void gemm_mfma(const u16* __restrict__ A, const u16* __restrict__ W,
               const u16* __restrict__ bias, void* __restrict__ C,
               int M, int N, int K, int obf, int brow,
               const int* __restrict__ flagp)
{
    if (*flagp != 1) return;
    __shared__ __align__(16) u16 At[128 * 32];
    __shared__ __align__(16) u16 Bt[128 * 32];

    const int t = threadIdx.x;
    const int w = t >> 6;
    const int lane = t & 63;
    const int wm = w >> 1, wn = w & 1;
    const int lr = lane & 15, quad = lane >> 4;
    const int bm = blockIdx.y * 128;
    const int bn = blockIdx.x * 128;
    const int srow = lane >> 2;
    const int scol = (lane & 3) * 8;

    f32x4 acc[4][4];
#pragma unroll
    for (int i = 0; i < 4; i++)
#pragma unroll
        for (int j = 0; j < 4; j++) acc[i][j] = (f32x4){0.f, 0.f, 0.f, 0.f};

    for (int k0 = 0; k0 < K; k0 += 32) {
        __syncthreads();
#pragma unroll
        for (int c = 2 * w; c < 2 * w + 2; c++) {
            const int row = c * 16 + srow;
            async_copy16(A + (size_t)(bm + row) * K + k0 + scol, &At[c * 512]);
            async_copy16(W + (size_t)(bn + row) * K + k0 + scol, &Bt[c * 512]);
        }
        __syncthreads();

        short8 av[4], bv[4];
#pragma unroll
        for (int i = 0; i < 4; i++)
            av[i] = *(const short8*)&At[(wm * 64 + i * 16 + lr) * 32 + quad * 8];
#pragma unroll
        for (int j = 0; j < 4; j++)
            bv[j] = *(const short8*)&Bt[(wn * 64 + j * 16 + lr) * 32 + quad * 8];
#pragma unroll
        for (int i = 0; i < 4; i++)
#pragma unroll
            for (int j = 0; j < 4; j++)
                acc[i][j] = __builtin_amdgcn_mfma_f32_16x16x32_bf16(av[i], bv[j], acc[i][j], 0, 0, 0);
    }

#pragma unroll
    for (int j = 0; j < 4; j++) {
        const int col = bn + wn * 64 + j * 16 + lr;
        const float bc = brow ? 0.f : b2f(bias[col]);
#pragma unroll
        for (int i = 0; i < 4; i++) {
            const int row0 = bm + wm * 64 + i * 16 + quad * 4;
#pragma unroll
            for (int r = 0; r < 4; r++) {
                const int row = row0 + r;
                const float bb = brow ? b2f(bias[row]) : bc;
                const float val = acc[i][j][r] + bb;
                if (obf) ((u16*)C)[(size_t)row * N + col] = f2b(val);
                else     ((float*)C)[(size_t)row * N + col] = val;
            }
        }
    }
}

// fp32 in -> RMSnorm + RoPE (+gain*scale) -> bf16 out
__global__ __launch_bounds__(64)
void norm_rope_bf(const float* __restrict__ src, u16* __restrict__ dst,
                  const u16* __restrict__ gain, int nheads, float scale,
                  const int* __restrict__ flagp)
{
    if (*flagp != 1) return;
    const int id = blockIdx.x;
    const int h  = id % nheads;
    const int bs = id / nheads;
    const int s  = bs & 2047;
    const float* v = src + (size_t)bs * nheads * 128 + h * 128;
    u16* o = dst + (size_t)bs * nheads * 128 + h * 128;
    const int i = threadIdx.x;

    float t1 = v[i];
    float t2 = v[i + 64];
    float ss = t1 * t1 + t2 * t2;
#pragma unroll
    for (int off = 32; off >= 1; off >>= 1) ss += __shfl_xor(ss, off);
    const float r = rsqrtf(ss * (1.0f / 128.0f) + 1.1920929e-07f);
    t1 *= r; t2 *= r;

    const float inv_freq = exp2f(-(float)i * 0.20762050593046014f);
    const float ph = (float)s * inv_freq;
    float sn, cs;
    __sincosf(ph, &sn, &cs);

    float g = scale;
    if (gain) g *= b2f(gain[h]);

    o[i]      = f2b((t1 * cs + t2 * sn) * g);
    o[i + 64] = f2b((-t1 * sn + t2 * cs) * g);
}

// MFMA flash attention, bf16. Q:[4096][2048], K:[4096][512], V^T:[512][4096].
// Block: 64 q-rows, 4 waves x 16 rows; KV tile = 64. Causal, GQA (h>>2).
// Scale+gain already folded into Q by norm_rope_bf.
__global__ __launch_bounds__(256)
void attn_mfma(const u16* __restrict__ Q, const u16* __restrict__ K,
               const u16* __restrict__ V, u16* __restrict__ O,
               const int* __restrict__ flagp)
{
    if (*flagp != 1) return;
    const int S = 2048, D = 2048, KVD = 512, MT = 4096;

    __shared__ __align__(16) u16 Ks[64 * 128];   // [k][d], XOR-swizzled rows
    __shared__ __align__(16) u16 Vt[128 * 64];   // [d][k], XOR-swizzled rows
    __shared__ __align__(16) u16 Ps[4][16][72];  // per-wave P, stride 144B

    const int t = threadIdx.x;
    const int w = t >> 6;
    const int lane = t & 63;
    const int lr = lane & 15, quad = lane >> 4;
    const int q0 = blockIdx.x * 64;
    const int h = blockIdx.y, b = blockIdx.z;
    const int kvh = h >> 2;

    // Q fragments held in registers for the whole block
    short8 qf[4];
    {
        const u16* qs = Q + (size_t)(b * S + q0 + w * 16 + lr) * D + h * 128;
#pragma unroll
        for (int kk = 0; kk < 4; kk++)
            qf[kk] = *(const short8*)(qs + kk * 32 + quad * 8);
    }

    f32x4 acc[8];
#pragma unroll
    for (int dt = 0; dt < 8; dt++) acc[dt] = (f32x4){0.f, 0.f, 0.f, 0.f};
    float mreg[4] = {-1e30f, -1e30f, -1e30f, -1e30f};
    float lreg[4] = {0.f, 0.f, 0.f, 0.f};

    // staging maps
    const int sr  = t >> 2;              // K row 0..63
    const int scc = (t & 3) * 64;        // K byte col base (4 x 16B each)
    const int vd  = t >> 1;              // V^T row (d) 0..127
    const int vcc = (t & 1) * 64;        // V^T byte col base
    const u16* kg = K + (size_t)(b * S + sr) * KVD + kvh * 128 + (t & 3) * 32;
    const u16* vg = V + (size_t)(kvh * 128 + vd) * MT + b * S + (t & 1) * 32;
    char* ksb = (char*)Ks;
    char* vtb = (char*)Vt;

    const int ntiles = q0 / 64 + 1;
    for (int kt = 0; kt < ntiles; kt++) {
        const int k0 = kt * 64;
        __syncthreads();
        {
            short8 kr[4], vr[4];
#pragma unroll
            for (int j = 0; j < 4; j++) {
                kr[j] = *(const short8*)(kg + (size_t)k0 * KVD + j * 8);
                vr[j] = *(const short8*)(vg + k0 + j * 8);
            }
#pragma unroll
            for (int j = 0; j < 4; j++) {
                const int ko = sr * 256 + scc + j * 16;
                *(short8*)(ksb + (ko ^ ((sr & 7) << 4))) = kr[j];
                const int vo = vd * 128 + vcc + j * 16;
                *(short8*)(vtb + (vo ^ ((vd & 7) << 4))) = vr[j];
            }
        }
        __syncthreads();

        // S = Q * K^T  (scale already in Q)
        f32x4 sacc[4];
#pragma unroll
        for (int ct = 0; ct < 4; ct++) sacc[ct] = (f32x4){0.f, 0.f, 0.f, 0.f};
#pragma unroll
        for (int ks = 0; ks < 4; ks++) {
            short8 kb[4];
#pragma unroll
            for (int ct = 0; ct < 4; ct++) {
                const int row = ct * 16 + lr;
                const int off = row * 256 + ks * 64 + quad * 16;
                kb[ct] = *(const short8*)(ksb + (off ^ ((row & 7) << 4)));
            }
#pragma unroll
            for (int ct = 0; ct < 4; ct++)
                sacc[ct] = __builtin_amdgcn_mfma_f32_16x16x32_bf16(qf[ks], kb[ct], sacc[ct], 0, 0, 0);
        }

        // online softmax; C-layout: row = quad*4+r, col = ct*16+lr
        const bool diag = (kt == ntiles - 1);
#pragma unroll
        for (int r = 0; r < 4; r++) {
            const int qg = q0 + w * 16 + quad * 4 + r;
            float s0 = sacc[0][r], s1 = sacc[1][r], s2 = sacc[2][r], s3 = sacc[3][r];
            if (diag) {
                if (k0 +  0 + lr > qg) s0 = -1e30f;
                if (k0 + 16 + lr > qg) s1 = -1e30f;
                if (k0 + 32 + lr > qg) s2 = -1e30f;
                if (k0 + 48 + lr > qg) s3 = -1e30f;
            }
            float mt = fmaxf(fmaxf(s0, s1), fmaxf(s2, s3));
#pragma unroll
            for (int off = 1; off < 16; off <<= 1) mt = fmaxf(mt, __shfl_xor(mt, off));
            const float mnew  = fmaxf(mreg[r], mt);
            const float alpha = __expf(mreg[r] - mnew);
            const float p0 = __expf(s0 - mnew);
            const float p1 = __expf(s1 - mnew);
            const float p2 = __expf(s2 - mnew);
            const float p3 = __expf(s3 - mnew);
            Ps[w][quad * 4 + r][ 0 + lr] = f2b(p0);
            Ps[w][quad * 4 + r][16 + lr] = f2b(p1);
            Ps[w][quad * 4 + r][32 + lr] = f2b(p2);
            Ps[w][quad * 4 + r][48 + lr] = f2b(p3);
            float ps = p0 + p1 + p2 + p3;
#pragma unroll
            for (int off = 1; off < 16; off <<= 1) ps += __shfl_xor(ps, off);
            lreg[r] = lreg[r] * alpha + ps;
            mreg[r] = mnew;
#pragma unroll
            for (int dt = 0; dt < 8; dt++) acc[dt][r] *= alpha;
        }

        // O += P * V   (A-frag from Ps, B-frag from swizzled V^T)
#pragma unroll
        for (int ks2 = 0; ks2 < 2; ks2++) {
            const short8 pa = *(const short8*)((const char*)&Ps[w][lr][0] + ks2 * 64 + quad * 16);
#pragma unroll
            for (int dt = 0; dt < 8; dt++) {
                const int vrow = dt * 16 + lr;
                const int off = vrow * 128 + ks2 * 64 + quad * 16;
                const short8 vb = *(const short8*)(vtb + (off ^ ((vrow & 7) << 4)));
                acc[dt] = __builtin_amdgcn_mfma_f32_16x16x32_bf16(pa, vb, acc[dt], 0, 0, 0);
            }
        }
    }

#pragma unroll
    for (int r = 0; r < 4; r++) {
        const float inv = 1.0f / lreg[r];
        u16* dst = O + (size_t)(b * S + q0 + w * 16 + quad * 4 + r) * D + h * 128 + lr;
#pragma unroll
        for (int dt = 0; dt < 8; dt++)
            dst[dt * 16] = f2b(acc[dt][r] * inv);
    }
}

// ---------------------------------------------------------------------------
extern "C" void kernel_launch(void* const* d_in, const int* in_sizes, int n_in,
                              void* d_out, int out_size, void* d_ws, size_t ws_size,
                              hipStream_t stream)
{
    const void* x  = d_in[0];
    const void* Wq = d_in[1];
    const void* bq = d_in[2];
    const void* Wk = d_in[3];
    const void* bk = d_in[4];
    const void* Wv = d_in[5];
    const void* bv = d_in[6];
    const void* Wo = d_in[7];
    const void* bo = d_in[8];
    const void* qg = d_in[9];

    const int B = 2, S = 2048, D = 2048, H = 16, KVH = 4, KVD = 512;
    const int M = B * S;   // 4096

    float* ws = (float*)d_ws;
    float* Qf = ws;                           // M*D fp32
    float* Kf = Qf + (size_t)M * D;           // M*KVD fp32
    float* Vf = Kf + (size_t)M * KVD;         // scalar-path V (fp32)
    float* Cf = Vf + (size_t)M * KVD;         // scalar-path ctx (fp32)
    int*  flag = (int*)(Cf + (size_t)M * D);  // same position as round-2

    // fast-path bf16 buffers carved from the (unused in fast path) Vf+Cf region:
    // 4.2M + 1.05M + 1.05M + 4.2M floats = exactly M*KVD + M*D floats.
    u16* Qb = (u16*)Vf;                       // M*D bf16
    u16* Kb = Qb + (size_t)M * D;             // M*KVD bf16
    u16* Vb = Kb + (size_t)M * KVD;           // V^T [KVD][M] bf16
    u16* Cb = Vb + (size_t)M * KVD;           // M*D bf16

    detect_dtype<<<1, 256, 0, stream>>>((const unsigned short*)x, 16384, flag);

    // ---------------- fast path (flag==1) ----------------
    // Q = x*Wq^T + bq  -> fp32 (pre-norm precision)
    gemm_mfma<<<dim3(D / 128, M / 128), 256, 0, stream>>>(
        (const u16*)x, (const u16*)Wq, (const u16*)bq, Qf, M, D, D, 0, 0, flag);
    // K = x*Wk^T + bk  -> fp32
    gemm_mfma<<<dim3(KVD / 128, M / 128), 256, 0, stream>>>(
        (const u16*)x, (const u16*)Wk, (const u16*)bk, Kf, M, KVD, D, 0, 0, flag);
    // V^T = Wv*x^T + bv (row bias) -> bf16 directly, K-contiguous for PV
    gemm_mfma<<<dim3(M / 128, KVD / 128), 256, 0, stream>>>(
        (const u16*)Wv, (const u16*)x, (const u16*)bv, Vb, KVD, M, D, 1, 1, flag);

    norm_rope_bf<<<M * H, 64, 0, stream>>>(Qf, Qb, (const u16*)qg, H,
                                           0.08838834764831845f, flag);
    norm_rope_bf<<<M * KVH, 64, 0, stream>>>(Kf, Kb, nullptr, KVH, 1.0f, flag);

    attn_mfma<<<dim3(S / 64, H, B), 256, 0, stream>>>(Qb, Kb, Vb, Cb, flag);

    gemm_mfma<<<dim3(D / 128, M / 128), 256, 0, stream>>>(
        Cb, (const u16*)Wo, (const u16*)bo, d_out, M, D, D, 1, 0, flag);

    // ---------------- scalar fallback (flag==0) ----------------
    gemm_bias<<<dim3(D / 128, M / 128), 256, 0, stream>>>(x, 1, Wq, bq, Qf, 0, M, D, D, flag);
    gemm_bias<<<dim3(KVD / 128, M / 128), 256, 0, stream>>>(x, 1, Wk, bk, Kf, 0, M, KVD, D, flag);
    gemm_bias<<<dim3(KVD / 128, M / 128), 256, 0, stream>>>(x, 1, Wv, bv, Vf, 0, M, KVD, D, flag);

    norm_rope<<<M * H, 64, 0, stream>>>(Qf, qg, H, 0.08838834764831845f, flag);
    norm_rope<<<M * KVH, 64, 0, stream>>>(Kf, nullptr, KVH, 1.0f, flag);

    attn_kernel<<<dim3(S / 32, H, B), 256, 0, stream>>>(Qf, Kf, Vf, Cf, flag);

    gemm_bias<<<dim3(D / 128, M / 128), 256, 0, stream>>>(Cf, 0, Wo, bo, d_out, 1, M, D, D, flag);
}

// Round 2
// 1222.888 us; speedup vs baseline: 3.4142x; 2.6332x over previous
//
#include <hip/hip_runtime.h>
#include <hip/hip_bf16.h>

typedef __hip_bfloat16 bf16;
typedef unsigned short u16;
typedef short short8 __attribute__((ext_vector_type(8)));
typedef float f32x4  __attribute__((ext_vector_type(4)));

static __device__ __forceinline__ float b2f(u16 u) {
    union { unsigned int i; float f; } c; c.i = (unsigned int)u << 16; return c.f;
}

// Runtime-dtype load/store: flag==1 -> bf16 inputs, 0 -> fp32 inputs.
static __device__ __forceinline__ float ldf(const void* p, size_t i, int isbf16) {
    return isbf16 ? __bfloat162float(((const bf16*)p)[i]) : ((const float*)p)[i];
}
static __device__ __forceinline__ void stf(void* p, size_t i, float v, int isbf16) {
    if (isbf16) ((bf16*)p)[i] = __float2bfloat16(v);
    else        ((float*)p)[i] = v;
}

// ---- split-bf16 packing: u32 = (hi bf16 bits << 16) | (lo bf16 bits) ----
// hi = truncate(v) to bf16; lo = truncate(v - hi).  v ~= hi + lo (2^-16 rel).
static __device__ __forceinline__ unsigned packf(float v) {
    unsigned ub = __float_as_uint(v);
    unsigned uh = ub & 0xFFFF0000u;
    float r = v - __uint_as_float(uh);
    return uh | (__float_as_uint(r) >> 16);
}
static __device__ __forceinline__ float unpackf(unsigned u) {
    return __uint_as_float(u & 0xFFFF0000u) + __uint_as_float(u << 16);
}

// unpack 8 packed u32 (two uint4) into hi-plane / lo-plane bf16x8
static __device__ __forceinline__ void upk8(uint4 a, uint4 b, short8& h, short8& l) {
    h = (short8){(short)(a.x >> 16), (short)(a.y >> 16), (short)(a.z >> 16), (short)(a.w >> 16),
                 (short)(b.x >> 16), (short)(b.y >> 16), (short)(b.z >> 16), (short)(b.w >> 16)};
    l = (short8){(short)(a.x), (short)(a.y), (short)(a.z), (short)(a.w),
                 (short)(b.x), (short)(b.y), (short)(b.z), (short)(b.w)};
}

// split 8 fp32 (two float4) into hi/lo bf16x8
static __device__ __forceinline__ void splitf8(float4 a, float4 b, short8& h, short8& l) {
    float vv[8] = {a.x, a.y, a.z, a.w, b.x, b.y, b.z, b.w};
    unsigned hh[8], ll[8];
#pragma unroll
    for (int j = 0; j < 8; j++) {
        unsigned ub = __float_as_uint(vv[j]);
        unsigned uh = ub & 0xFFFF0000u;
        float r = vv[j] - __uint_as_float(uh);
        hh[j] = uh >> 16;
        ll[j] = __float_as_uint(r) >> 16;
    }
    h = (short8){(short)hh[0], (short)hh[1], (short)hh[2], (short)hh[3],
                 (short)hh[4], (short)hh[5], (short)hh[6], (short)hh[7]};
    l = (short8){(short)ll[0], (short)ll[1], (short)ll[2], (short)ll[3],
                 (short)ll[4], (short)ll[5], (short)ll[6], (short)ll[7]};
}

// load 16 contiguous elements -> hi/lo planes.  AK: 0 = raw input (dtype per f),
// 1 = packed-u32 tensor (our own intermediates).
template<int AK>
static __device__ __forceinline__ void load_split(const void* P, size_t e, int f,
        short8& h0, short8& h1, short8& l0, short8& l1)
{
    if (AK == 1) {
        const uint4* p = (const uint4*)((const unsigned*)P + e);
        uint4 a = p[0], b = p[1], c = p[2], d = p[3];
        upk8(a, b, h0, l0);
        upk8(c, d, h1, l1);
    } else if (f == 0) {
        const float4* p = (const float4*)((const float*)P + e);
        float4 a = p[0], b = p[1], c = p[2], d = p[3];
        splitf8(a, b, h0, l0);
        splitf8(c, d, h1, l1);
    } else {
        const short8* p = (const short8*)((const u16*)P + e);
        h0 = p[0]; h1 = p[1];
        l0 = (short8){0,0,0,0,0,0,0,0};
        l1 = (short8){0,0,0,0,0,0,0,0};
    }
}

// ---------------------------------------------------------------------------
// dtype detection (verbatim from passing rounds)
// ---------------------------------------------------------------------------
__global__ void detect_dtype(const unsigned short* __restrict__ x, int n, int* __restrict__ flag)
{
    __shared__ int cnt;
    if (threadIdx.x == 0) cnt = 0;
    __syncthreads();
    int local = 0;
    for (int i = threadIdx.x; i < n; i += blockDim.x) {
        const unsigned int e = (x[i] >> 7) & 0xFF;
        if (e >= 134u) local++;
    }
    atomicAdd(&cnt, local);
    __syncthreads();
    if (threadIdx.x == 0) *flag = (cnt >= 32) ? 0 : 1;
}

// ---------------------------------------------------------------------------
// split-bf16 MFMA GEMM core.  C[m][n] = sum_k A[m][k]*W[n][k] + bias
// A = Ah+Al, W = Wh+Wl; 3 MFMA per fragment pair (drop lo*lo).
// OUT: 1 = packed u32, 2 = stf to output (dtype per flag).
// BROW: bias indexed by row (for the V^T gemm).
// ---------------------------------------------------------------------------
template<int AK, int OUT, int BROW>
static __device__ __forceinline__ void gemm_core(
    const void* __restrict__ A, const void* __restrict__ W,
    const void* __restrict__ bias, void* __restrict__ C,
    int M, int N, int K, int f, int bx, int by, u16* sm)
{
    u16* Ah = sm;
    u16* Al = sm + 4096;
    u16* Wh = sm + 8192;
    u16* Wl = sm + 12288;

    const int t = threadIdx.x;
    const int w = t >> 6, lane = t & 63;
    const int wm = w >> 1, wn = w & 1;
    const int lr = lane & 15, quad = lane >> 4;
    const int bm = by * 128, bn = bx * 128;
    const int srow = t >> 1;          // 0..127
    const int scol = (t & 1) * 16;    // 0 or 16

    f32x4 acc[4][4];
#pragma unroll
    for (int i = 0; i < 4; i++)
#pragma unroll
        for (int j = 0; j < 4; j++) acc[i][j] = (f32x4){0.f, 0.f, 0.f, 0.f};

    for (int k0 = 0; k0 < K; k0 += 32) {
        short8 ah0, ah1, al0, al1, wh0, wh1, wl0, wl1;
        load_split<AK>(A, (size_t)(bm + srow) * K + k0 + scol, f, ah0, ah1, al0, al1);
        load_split<0>(W, (size_t)(bn + srow) * K + k0 + scol, f, wh0, wh1, wl0, wl1);
        __syncthreads();
        {
            const int o = srow * 32 + scol;
            *(short8*)&Ah[o] = ah0; *(short8*)&Ah[o + 8] = ah1;
            *(short8*)&Al[o] = al0; *(short8*)&Al[o + 8] = al1;
            *(short8*)&Wh[o] = wh0; *(short8*)&Wh[o + 8] = wh1;
            *(short8*)&Wl[o] = wl0; *(short8*)&Wl[o + 8] = wl1;
        }
        __syncthreads();

        short8 avh[4], avl[4], bvh[4], bvl[4];
#pragma unroll
        for (int i = 0; i < 4; i++) {
            const int o = (wm * 64 + i * 16 + lr) * 32 + quad * 8;
            avh[i] = *(const short8*)&Ah[o];
            avl[i] = *(const short8*)&Al[o];
        }
#pragma unroll
        for (int j = 0; j < 4; j++) {
            const int o = (wn * 64 + j * 16 + lr) * 32 + quad * 8;
            bvh[j] = *(const short8*)&Wh[o];
            bvl[j] = *(const short8*)&Wl[o];
        }
#pragma unroll
        for (int i = 0; i < 4; i++)
#pragma unroll
            for (int j = 0; j < 4; j++) {
                acc[i][j] = __builtin_amdgcn_mfma_f32_16x16x32_bf16(avl[i], bvh[j], acc[i][j], 0, 0, 0);
                acc[i][j] = __builtin_amdgcn_mfma_f32_16x16x32_bf16(avh[i], bvl[j], acc[i][j], 0, 0, 0);
                acc[i][j] = __builtin_amdgcn_mfma_f32_16x16x32_bf16(avh[i], bvh[j], acc[i][j], 0, 0, 0);
            }
    }

#pragma unroll
    for (int j = 0; j < 4; j++) {
        const int col = bn + wn * 64 + j * 16 + lr;
        const float bc = BROW ? 0.f : ldf(bias, col, f);
#pragma unroll
        for (int i = 0; i < 4; i++) {
            const int row0 = bm + wm * 64 + i * 16 + quad * 4;
#pragma unroll
            for (int r = 0; r < 4; r++) {
                const int row = row0 + r;
                const float bb = BROW ? ldf(bias, row, f) : bc;
                const float val = acc[i][j][r] + bb;
                if (OUT == 1) ((unsigned*)C)[(size_t)row * N + col] = packf(val);
                else          stf(C, (size_t)row * N + col, val, f);
            }
        }
    }
}

template<int AK, int OUT, int BROW>
__global__ __launch_bounds__(256)
void gemm3(const void* __restrict__ A, const void* __restrict__ W,
           const void* __restrict__ bias, void* __restrict__ C,
           int M, int N, int K, const int* __restrict__ flagp)
{
    extern __shared__ u16 sm[];
    gemm_core<AK, OUT, BROW>(A, W, bias, C, M, N, K, *flagp, blockIdx.x, blockIdx.y, sm);
}

// K-projection (128 blocks) and V^T-projection (128 blocks) fused into one
// 256-block launch so both halves of the GPU stay busy.
__global__ __launch_bounds__(256)
void gemm_kv(const void* __restrict__ x,
             const void* __restrict__ Wk, const void* __restrict__ bk, unsigned* __restrict__ Kp,
             const void* __restrict__ Wv, const void* __restrict__ bv, unsigned* __restrict__ Vtp,
             const int* __restrict__ flagp)
{
    extern __shared__ u16 sm[];
    const int f = *flagp;
    if (blockIdx.x < 4)
        gemm_core<0, 1, 0>(x, Wk, bk, Kp, 4096, 512, 2048, f, blockIdx.x, blockIdx.y, sm);
    else
        gemm_core<0, 1, 1>(Wv, x, bv, Vtp, 512, 4096, 2048, f, blockIdx.y, blockIdx.x - 4, sm);
}

// ---------------------------------------------------------------------------
// RMSnorm + RoPE (+gain*scale), in-place on a packed hi|lo tensor.
// ---------------------------------------------------------------------------
__global__ __launch_bounds__(64)
void norm_rope_pk(unsigned* __restrict__ buf, const void* __restrict__ gain,
                  int nheads, float scale, const int* __restrict__ flagp)
{
    const int id = blockIdx.x;
    const int h  = id % nheads;
    const int bs = id / nheads;
    const int s  = bs & 2047;
    unsigned* v = buf + (size_t)bs * nheads * 128 + h * 128;
    const int i = threadIdx.x;

    float t1 = unpackf(v[i]);
    float t2 = unpackf(v[i + 64]);
    float ss = t1 * t1 + t2 * t2;
#pragma unroll
    for (int off = 32; off >= 1; off >>= 1) ss += __shfl_xor(ss, off);
    const float r = rsqrtf(ss * (1.0f / 128.0f) + 1.1920929e-07f);
    t1 *= r; t2 *= r;

    const float inv_freq = exp2f(-(float)i * 0.20762050593046014f);
    const float ph = (float)s * inv_freq;
    float sn, cs;
    __sincosf(ph, &sn, &cs);

    float g = scale;
    if (gain) g *= ldf(gain, h, *flagp);

    v[i]      = packf((t1 * cs + t2 * sn) * g);
    v[i + 64] = packf((-t1 * sn + t2 * cs) * g);
}

// ---------------------------------------------------------------------------
// split-bf16 MFMA flash attention.
// Qp:[4096][2048] packed, Kp:[4096][512] packed, Vtp:[512][4096] packed (V^T),
// Cp:[4096][2048] packed out.  64 q-rows/block, 4 waves x 16 rows, KV tile 64.
// Causal, GQA (kvh = h>>2).  Scale+gain already folded into Q.
// QK^T: qh*kh + qh*kl + ql*kh.  PV: two passes (Ph then Pl) sharing one P buf.
// ---------------------------------------------------------------------------
__global__ __launch_bounds__(256)
void attn3(const unsigned* __restrict__ Qp, const unsigned* __restrict__ Kp,
           const unsigned* __restrict__ Vtp, unsigned* __restrict__ Cp)
{
    const int S = 2048, D = 2048, KVD = 512, MT = 4096;

    __shared__ __align__(16) u16 Kh[64 * 128], Kl[64 * 128];   // [k][d], XOR-swizzled
    __shared__ __align__(16) u16 Vh[128 * 64], Vl[128 * 64];   // [d][k], XOR-swizzled
    __shared__ __align__(16) u16 Ps[4][16][72];                // per-wave P plane

    const int t = threadIdx.x, w = t >> 6, lane = t & 63;
    const int lr = lane & 15, quad = lane >> 4;
    const int q0 = blockIdx.x * 64;
    const int h = blockIdx.y, b = blockIdx.z;
    const int kvh = h >> 2;

    // Q fragments (hi/lo) in registers for the whole block
    short8 qh[4], ql[4];
    {
        const unsigned* qs = Qp + (size_t)(b * S + q0 + w * 16 + lr) * D + h * 128;
#pragma unroll
        for (int kk = 0; kk < 4; kk++) {
            const uint4* p = (const uint4*)(qs + kk * 32 + quad * 8);
            upk8(p[0], p[1], qh[kk], ql[kk]);
        }
    }

    f32x4 acc[8];
#pragma unroll
    for (int dt = 0; dt < 8; dt++) acc[dt] = (f32x4){0.f, 0.f, 0.f, 0.f};
    float mreg[4] = {-1e30f, -1e30f, -1e30f, -1e30f};
    float lreg[4] = {0.f, 0.f, 0.f, 0.f};

    // staging maps
    const int kr = t >> 2, kq = t & 3;      // K: row 0..63, col-quarter
    const int vd = t >> 1, vh2 = t & 1;     // V^T: row (d) 0..127, col-half
    const unsigned* kg = Kp + (size_t)(b * S + kr) * KVD + kvh * 128 + kq * 32;
    const unsigned* vg = Vtp + (size_t)(kvh * 128 + vd) * MT + b * S + vh2 * 32;
    char* KhB = (char*)Kh; char* KlB = (char*)Kl;
    char* VhB = (char*)Vh; char* VlB = (char*)Vl;

    const int ntiles = q0 / 64 + 1;
    for (int kt = 0; kt < ntiles; kt++) {
        const int k0 = kt * 64;

        // global loads first (overlap with previous tile's MFMAs)
        uint4 kv[8], vv[8];
#pragma unroll
        for (int u = 0; u < 8; u++) {
            kv[u] = *(const uint4*)(kg + (size_t)k0 * KVD + u * 4);
            vv[u] = *(const uint4*)(vg + k0 + u * 4);
        }
        __syncthreads();
#pragma unroll
        for (int u2 = 0; u2 < 4; u2++) {
            short8 hh, ll;
            upk8(kv[2 * u2], kv[2 * u2 + 1], hh, ll);
            const int ko = (kr * 256 + kq * 64 + u2 * 16) ^ ((kr & 7) << 4);
            *(short8*)(KhB + ko) = hh;
            *(short8*)(KlB + ko) = ll;
            upk8(vv[2 * u2], vv[2 * u2 + 1], hh, ll);
            const int vo = (vd * 128 + vh2 * 64 + u2 * 16) ^ ((vd & 7) << 4);
            *(short8*)(VhB + vo) = hh;
            *(short8*)(VlB + vo) = ll;
        }
        __syncthreads();

        // S = Q*K^T  (3-product split)
        f32x4 sacc[4];
#pragma unroll
        for (int ct = 0; ct < 4; ct++) sacc[ct] = (f32x4){0.f, 0.f, 0.f, 0.f};
#pragma unroll
        for (int ks = 0; ks < 4; ks++) {
            short8 kbh[4], kbl[4];
#pragma unroll
            for (int ct = 0; ct < 4; ct++) {
                const int row = ct * 16 + lr;
                const int off = (row * 256 + ks * 64 + quad * 16) ^ ((row & 7) << 4);
                kbh[ct] = *(const short8*)(KhB + off);
                kbl[ct] = *(const short8*)(KlB + off);
            }
#pragma unroll
            for (int ct = 0; ct < 4; ct++) {
                sacc[ct] = __builtin_amdgcn_mfma_f32_16x16x32_bf16(ql[ks], kbh[ct], sacc[ct], 0, 0, 0);
                sacc[ct] = __builtin_amdgcn_mfma_f32_16x16x32_bf16(qh[ks], kbl[ct], sacc[ct], 0, 0, 0);
                sacc[ct] = __builtin_amdgcn_mfma_f32_16x16x32_bf16(qh[ks], kbh[ct], sacc[ct], 0, 0, 0);
            }
        }

        // online softmax; C-layout: row = quad*4+r, col = ct*16+lr
        const bool diag = (kt == ntiles - 1);
        float p[4][4];
#pragma unroll
        for (int r = 0; r < 4; r++) {
            const int qg = q0 + w * 16 + quad * 4 + r;
            float s0 = sacc[0][r], s1 = sacc[1][r], s2 = sacc[2][r], s3 = sacc[3][r];
            if (diag) {
                if (k0 +  0 + lr > qg) s0 = -1e30f;
                if (k0 + 16 + lr > qg) s1 = -1e30f;
                if (k0 + 32 + lr > qg) s2 = -1e30f;
                if (k0 + 48 + lr > qg) s3 = -1e30f;
            }
            float mt = fmaxf(fmaxf(s0, s1), fmaxf(s2, s3));
#pragma unroll
            for (int off = 1; off < 16; off <<= 1) mt = fmaxf(mt, __shfl_xor(mt, off));
            const float mnew  = fmaxf(mreg[r], mt);
            const float alpha = __expf(mreg[r] - mnew);
            p[r][0] = (s0 <= -1e29f) ? 0.f : __expf(s0 - mnew);
            p[r][1] = (s1 <= -1e29f) ? 0.f : __expf(s1 - mnew);
            p[r][2] = (s2 <= -1e29f) ? 0.f : __expf(s2 - mnew);
            p[r][3] = (s3 <= -1e29f) ? 0.f : __expf(s3 - mnew);
            float ps = p[r][0] + p[r][1] + p[r][2] + p[r][3];
#pragma unroll
            for (int off = 1; off < 16; off <<= 1) ps += __shfl_xor(ps, off);
            lreg[r] = lreg[r] * alpha + ps;
            mreg[r] = mnew;
#pragma unroll
            for (int dt = 0; dt < 8; dt++) acc[dt][r] *= alpha;
        }

        // ---- PV pass 1: P_hi * (V_hi + V_lo) ----
#pragma unroll
        for (int r = 0; r < 4; r++)
#pragma unroll
            for (int ct = 0; ct < 4; ct++)
                Ps[w][quad * 4 + r][ct * 16 + lr] = (u16)(__float_as_uint(p[r][ct]) >> 16);
#pragma unroll
        for (int ks2 = 0; ks2 < 2; ks2++) {
            const short8 pa = *(const short8*)((const char*)&Ps[w][lr][0] + ks2 * 64 + quad * 16);
#pragma unroll
            for (int dt = 0; dt < 8; dt++) {
                const int vrow = dt * 16 + lr;
                const int off = (vrow * 128 + ks2 * 64 + quad * 16) ^ ((vrow & 7) << 4);
                const short8 vbh = *(const short8*)(VhB + off);
                const short8 vbl = *(const short8*)(VlB + off);
                acc[dt] = __builtin_amdgcn_mfma_f32_16x16x32_bf16(pa, vbh, acc[dt], 0, 0, 0);
                acc[dt] = __builtin_amdgcn_mfma_f32_16x16x32_bf16(pa, vbl, acc[dt], 0, 0, 0);
            }
        }
        // ---- PV pass 2: P_lo * V_hi (same-wave LDS reuse; DS ops are in-order) ----
#pragma unroll
        for (int r = 0; r < 4; r++)
#pragma unroll
            for (int ct = 0; ct < 4; ct++) {
                const unsigned ub = __float_as_uint(p[r][ct]);
                const unsigned uh = ub & 0xFFFF0000u;
                const float rr = p[r][ct] - __uint_as_float(uh);
                Ps[w][quad * 4 + r][ct * 16 + lr] = (u16)(__float_as_uint(rr) >> 16);
            }
#pragma unroll
        for (int ks2 = 0; ks2 < 2; ks2++) {
            const short8 pa = *(const short8*)((const char*)&Ps[w][lr][0] + ks2 * 64 + quad * 16);
#pragma unroll
            for (int dt = 0; dt < 8; dt++) {
                const int vrow = dt * 16 + lr;
                const int off = (vrow * 128 + ks2 * 64 + quad * 16) ^ ((vrow & 7) << 4);
                const short8 vbh = *(const short8*)(VhB + off);
                acc[dt] = __builtin_amdgcn_mfma_f32_16x16x32_bf16(pa, vbh, acc[dt], 0, 0, 0);
            }
        }
    }

#pragma unroll
    for (int r = 0; r < 4; r++) {
        const float inv = 1.0f / lreg[r];
        unsigned* dst = Cp + (size_t)(b * S + q0 + w * 16 + quad * 4 + r) * D + h * 128 + lr;
#pragma unroll
        for (int dt = 0; dt < 8; dt++)
            dst[dt * 16] = packf(acc[dt][r] * inv);
    }
}

// ---------------------------------------------------------------------------
extern "C" void kernel_launch(void* const* d_in, const int* in_sizes, int n_in,
                              void* d_out, int out_size, void* d_ws, size_t ws_size,
                              hipStream_t stream)
{
    const void* x  = d_in[0];
    const void* Wq = d_in[1];
    const void* bq = d_in[2];
    const void* Wk = d_in[3];
    const void* bk = d_in[4];
    const void* Wv = d_in[5];
    const void* bv = d_in[6];
    const void* Wo = d_in[7];
    const void* bo = d_in[8];
    const void* qg = d_in[9];

    const int B = 2, S = 2048, D = 2048, H = 16, KVH = 4, KVD = 512;
    const int M = B * S;   // 4096

    // packed hi|lo u32 tensors — total footprint identical to the proven
    // round-2 layout (83.9 MB), flag at the same offset.
    unsigned* Qp  = (unsigned*)d_ws;              // [M][D]
    unsigned* Kp  = Qp + (size_t)M * D;           // [M][KVD]
    unsigned* Vtp = Kp + (size_t)M * KVD;         // [KVD][M]  (V^T)
    unsigned* Cp  = Vtp + (size_t)KVD * M;        // [M][D]
    int* flag = (int*)(Cp + (size_t)M * D);

    detect_dtype<<<1, 256, 0, stream>>>((const unsigned short*)x, 16384, flag);

    // Q = x*Wq^T + bq -> packed (pre-norm)
    gemm3<0, 1, 0><<<dim3(D / 128, M / 128), 256, 32768, stream>>>(
        x, Wq, bq, Qp, M, D, D, flag);
    // K = x*Wk^T + bk -> packed ; V^T = Wv*x^T + bv (row bias) -> packed
    gemm_kv<<<dim3(8, 32), 256, 32768, stream>>>(x, Wk, bk, Kp, Wv, bv, Vtp, flag);

    // RMSnorm + RoPE in-place (scale*gain folded into Q)
    norm_rope_pk<<<M * H, 64, 0, stream>>>(Qp, qg, H, 0.08838834764831845f, flag);
    norm_rope_pk<<<M * KVH, 64, 0, stream>>>(Kp, nullptr, KVH, 1.0f, flag);

    attn3<<<dim3(S / 64, H, B), 256, 0, stream>>>(Qp, Kp, Vtp, Cp);

    // out = ctx*Wo^T + bo -> d_out (dtype follows input)
    gemm3<1, 2, 0><<<dim3(D / 128, M / 128), 256, 32768, stream>>>(
        Cp, Wo, bo, d_out, M, D, D, flag);
}

// Round 3
// 716.401 us; speedup vs baseline: 5.8280x; 1.7070x over previous
//
#include <hip/hip_runtime.h>
#include <hip/hip_bf16.h>

typedef __hip_bfloat16 bf16;
typedef unsigned short u16;
typedef short short8 __attribute__((ext_vector_type(8)));
typedef float f32x4  __attribute__((ext_vector_type(4)));

// Runtime-dtype load/store: flag==1 -> bf16 inputs, 0 -> fp32 inputs.
static __device__ __forceinline__ float ldf(const void* p, size_t i, int isbf16) {
    return isbf16 ? __bfloat162float(((const bf16*)p)[i]) : ((const float*)p)[i];
}
static __device__ __forceinline__ void stf(void* p, size_t i, float v, int isbf16) {
    if (isbf16) ((bf16*)p)[i] = __float2bfloat16(v);
    else        ((float*)p)[i] = v;
}

// ---- split-bf16 packing: u32 = (hi bf16 bits << 16) | (lo bf16 bits) ----
static __device__ __forceinline__ unsigned packf(float v) {
    unsigned ub = __float_as_uint(v);
    unsigned uh = ub & 0xFFFF0000u;
    float r = v - __uint_as_float(uh);
    return uh | (__float_as_uint(r) >> 16);
}
static __device__ __forceinline__ float unpackf(unsigned u) {
    return __uint_as_float(u & 0xFFFF0000u) + __uint_as_float(u << 16);
}

// unpack 8 packed u32 (two uint4) into hi-plane / lo-plane bf16x8
static __device__ __forceinline__ void upk8(uint4 a, uint4 b, short8& h, short8& l) {
    h = (short8){(short)(a.x >> 16), (short)(a.y >> 16), (short)(a.z >> 16), (short)(a.w >> 16),
                 (short)(b.x >> 16), (short)(b.y >> 16), (short)(b.z >> 16), (short)(b.w >> 16)};
    l = (short8){(short)(a.x), (short)(a.y), (short)(a.z), (short)(a.w),
                 (short)(b.x), (short)(b.y), (short)(b.z), (short)(b.w)};
}

// split 8 fp32 (two float4) into hi/lo bf16x8
static __device__ __forceinline__ void splitf8(float4 a, float4 b, short8& h, short8& l) {
    float vv[8] = {a.x, a.y, a.z, a.w, b.x, b.y, b.z, b.w};
    unsigned hh[8], ll[8];
#pragma unroll
    for (int j = 0; j < 8; j++) {
        unsigned ub = __float_as_uint(vv[j]);
        unsigned uh = ub & 0xFFFF0000u;
        float r = vv[j] - __uint_as_float(uh);
        hh[j] = uh >> 16;
        ll[j] = __float_as_uint(r) >> 16;
    }
    h = (short8){(short)hh[0], (short)hh[1], (short)hh[2], (short)hh[3],
                 (short)hh[4], (short)hh[5], (short)hh[6], (short)hh[7]};
    l = (short8){(short)ll[0], (short)ll[1], (short)ll[2], (short)ll[3],
                 (short)ll[4], (short)ll[5], (short)ll[6], (short)ll[7]};
}

static __device__ __forceinline__ float4 u2f4(uint4 a) {
    return (float4){__uint_as_float(a.x), __uint_as_float(a.y),
                    __uint_as_float(a.z), __uint_as_float(a.w)};
}
static __device__ __forceinline__ short8 u4_s8(uint4 a) {
    return (short8){(short)(a.x & 0xFFFF), (short)(a.x >> 16),
                    (short)(a.y & 0xFFFF), (short)(a.y >> 16),
                    (short)(a.z & 0xFFFF), (short)(a.z >> 16),
                    (short)(a.w & 0xFFFF), (short)(a.w >> 16)};
}

// raw 64B (or 32B for bf16) load of 16 elements into uint4[4]
template<int AK>
static __device__ __forceinline__ void load_raw(const void* P, size_t e, int f, uint4* r) {
    if (AK == 1) {
        const uint4* p = (const uint4*)((const unsigned*)P + e);
        r[0] = p[0]; r[1] = p[1]; r[2] = p[2]; r[3] = p[3];
    } else if (f == 0) {
        const uint4* p = (const uint4*)((const float*)P + e);
        r[0] = p[0]; r[1] = p[1]; r[2] = p[2]; r[3] = p[3];
    } else {
        const uint4* p = (const uint4*)((const u16*)P + e);
        r[0] = p[0]; r[1] = p[1];
        r[2] = (uint4){0, 0, 0, 0}; r[3] = (uint4){0, 0, 0, 0};
    }
}

template<int AK>
static __device__ __forceinline__ void conv_raw(const uint4* r, int f,
        short8& h0, short8& h1, short8& l0, short8& l1) {
    if (AK == 1) {
        upk8(r[0], r[1], h0, l0);
        upk8(r[2], r[3], h1, l1);
    } else if (f == 0) {
        splitf8(u2f4(r[0]), u2f4(r[1]), h0, l0);
        splitf8(u2f4(r[2]), u2f4(r[3]), h1, l1);
    } else {
        h0 = u4_s8(r[0]); h1 = u4_s8(r[1]);
        l0 = (short8){0,0,0,0,0,0,0,0};
        l1 = (short8){0,0,0,0,0,0,0,0};
    }
}

// ---------------------------------------------------------------------------
// dtype detection (verbatim from passing rounds)
// ---------------------------------------------------------------------------
__global__ void detect_dtype(const unsigned short* __restrict__ x, int n, int* __restrict__ flag)
{
    __shared__ int cnt;
    if (threadIdx.x == 0) cnt = 0;
    __syncthreads();
    int local = 0;
    for (int i = threadIdx.x; i < n; i += blockDim.x) {
        const unsigned int e = (x[i] >> 7) & 0xFF;
        if (e >= 134u) local++;
    }
    atomicAdd(&cnt, local);
    __syncthreads();
    if (threadIdx.x == 0) *flag = (cnt >= 32) ? 0 : 1;
}

// ---------------------------------------------------------------------------
// split-bf16 MFMA GEMM core with register prefetch of the next k-tile.
// C[m][n] = sum_k A[m][k]*W[n][k] + bias.  3 MFMA per fragment pair.
// OUT: 1 = packed u32, 2 = stf to output (dtype per flag).
// BROW: bias indexed by row (for the V^T gemm).
// ---------------------------------------------------------------------------
template<int AK, int OUT, int BROW>
static __device__ __forceinline__ void gemm_core(
    const void* __restrict__ A, const void* __restrict__ W,
    const void* __restrict__ bias, void* __restrict__ C,
    int M, int N, int K, int f, int bx, int by, u16* sm)
{
    u16* Ah = sm;
    u16* Al = sm + 4096;
    u16* Wh = sm + 8192;
    u16* Wl = sm + 12288;

    const int t = threadIdx.x;
    const int w = t >> 6, lane = t & 63;
    const int wm = w >> 1, wn = w & 1;
    const int lr = lane & 15, quad = lane >> 4;
    const int bm = by * 128, bn = bx * 128;
    const int srow = t >> 1;          // 0..127
    const int scol = (t & 1) * 16;    // 0 or 16

    f32x4 acc[4][4];
#pragma unroll
    for (int i = 0; i < 4; i++)
#pragma unroll
        for (int j = 0; j < 4; j++) acc[i][j] = (f32x4){0.f, 0.f, 0.f, 0.f};

    uint4 ar[4], wr2[4];
    const size_t abase = (size_t)(bm + srow) * K + scol;
    const size_t wbase = (size_t)(bn + srow) * K + scol;
    load_raw<AK>(A, abase, f, ar);
    load_raw<0>(W, wbase, f, wr2);

    for (int k0 = 0; k0 < K; k0 += 32) {
        __syncthreads();
        {
            short8 h0, h1, l0, l1;
            conv_raw<AK>(ar, f, h0, h1, l0, l1);
            const int o = srow * 32 + scol;
            *(short8*)&Ah[o] = h0; *(short8*)&Ah[o + 8] = h1;
            *(short8*)&Al[o] = l0; *(short8*)&Al[o + 8] = l1;
            conv_raw<0>(wr2, f, h0, h1, l0, l1);
            *(short8*)&Wh[o] = h0; *(short8*)&Wh[o + 8] = h1;
            *(short8*)&Wl[o] = l0; *(short8*)&Wl[o + 8] = l1;
        }
        __syncthreads();
        if (k0 + 32 < K) {
            load_raw<AK>(A, abase + k0 + 32, f, ar);
            load_raw<0>(W, wbase + k0 + 32, f, wr2);
        }

        short8 avh[4], avl[4], bvh[4], bvl[4];
#pragma unroll
        for (int i = 0; i < 4; i++) {
            const int o = (wm * 64 + i * 16 + lr) * 32 + quad * 8;
            avh[i] = *(const short8*)&Ah[o];
            avl[i] = *(const short8*)&Al[o];
        }
#pragma unroll
        for (int j = 0; j < 4; j++) {
            const int o = (wn * 64 + j * 16 + lr) * 32 + quad * 8;
            bvh[j] = *(const short8*)&Wh[o];
            bvl[j] = *(const short8*)&Wl[o];
        }
        __builtin_amdgcn_s_setprio(1);
#pragma unroll
        for (int i = 0; i < 4; i++)
#pragma unroll
            for (int j = 0; j < 4; j++) {
                acc[i][j] = __builtin_amdgcn_mfma_f32_16x16x32_bf16(avl[i], bvh[j], acc[i][j], 0, 0, 0);
                acc[i][j] = __builtin_amdgcn_mfma_f32_16x16x32_bf16(avh[i], bvl[j], acc[i][j], 0, 0, 0);
                acc[i][j] = __builtin_amdgcn_mfma_f32_16x16x32_bf16(avh[i], bvh[j], acc[i][j], 0, 0, 0);
            }
        __builtin_amdgcn_s_setprio(0);
    }

#pragma unroll
    for (int j = 0; j < 4; j++) {
        const int col = bn + wn * 64 + j * 16 + lr;
        const float bc = BROW ? 0.f : ldf(bias, col, f);
#pragma unroll
        for (int i = 0; i < 4; i++) {
            const int row0 = bm + wm * 64 + i * 16 + quad * 4;
#pragma unroll
            for (int r = 0; r < 4; r++) {
                const int row = row0 + r;
                const float bb = BROW ? ldf(bias, row, f) : bc;
                const float val = acc[i][j][r] + bb;
                if (OUT == 1) ((unsigned*)C)[(size_t)row * N + col] = packf(val);
                else          stf(C, (size_t)row * N + col, val, f);
            }
        }
    }
}

template<int AK, int OUT, int BROW>
__global__ __launch_bounds__(256, 2)
void gemm3(const void* __restrict__ A, const void* __restrict__ W,
           const void* __restrict__ bias, void* __restrict__ C,
           int M, int N, int K, const int* __restrict__ flagp)
{
    extern __shared__ u16 sm[];
    gemm_core<AK, OUT, BROW>(A, W, bias, C, M, N, K, *flagp, blockIdx.x, blockIdx.y, sm);
}

// K-projection (128 blocks) and V^T-projection (128 blocks) fused.
__global__ __launch_bounds__(256, 2)
void gemm_kv(const void* __restrict__ x,
             const void* __restrict__ Wk, const void* __restrict__ bk, unsigned* __restrict__ Kp,
             const void* __restrict__ Wv, const void* __restrict__ bv, unsigned* __restrict__ Vtp,
             const int* __restrict__ flagp)
{
    extern __shared__ u16 sm[];
    const int f = *flagp;
    if (blockIdx.x < 4)
        gemm_core<0, 1, 0>(x, Wk, bk, Kp, 4096, 512, 2048, f, blockIdx.x, blockIdx.y, sm);
    else
        gemm_core<0, 1, 1>(Wv, x, bv, Vtp, 512, 4096, 2048, f, blockIdx.y, blockIdx.x - 4, sm);
}

// ---------------------------------------------------------------------------
// RMSnorm + RoPE (+gain*scale), in-place on a packed hi|lo tensor.
// ---------------------------------------------------------------------------
__global__ __launch_bounds__(64)
void norm_rope_pk(unsigned* __restrict__ buf, const void* __restrict__ gain,
                  int nheads, float scale, const int* __restrict__ flagp)
{
    const int id = blockIdx.x;
    const int h  = id % nheads;
    const int bs = id / nheads;
    const int s  = bs & 2047;
    unsigned* v = buf + (size_t)bs * nheads * 128 + h * 128;
    const int i = threadIdx.x;

    float t1 = unpackf(v[i]);
    float t2 = unpackf(v[i + 64]);
    float ss = t1 * t1 + t2 * t2;
#pragma unroll
    for (int off = 32; off >= 1; off >>= 1) ss += __shfl_xor(ss, off);
    const float r = rsqrtf(ss * (1.0f / 128.0f) + 1.1920929e-07f);
    t1 *= r; t2 *= r;

    const float inv_freq = exp2f(-(float)i * 0.20762050593046014f);
    const float ph = (float)s * inv_freq;
    float sn, cs;
    __sincosf(ph, &sn, &cs);

    float g = scale;
    if (gain) g *= ldf(gain, h, *flagp);

    v[i]      = packf((t1 * cs + t2 * sn) * g);
    v[i + 64] = packf((-t1 * sn + t2 * cs) * g);
}

// ---------------------------------------------------------------------------
// split-bf16 MFMA flash attention, pipelined + causally-paired.
// Qp:[4096][2048], Kp:[4096][512], Vtp:[512][4096] (V^T), Cp out — all packed.
// grid (16, H, B): block x handles q-tiles x AND 31-x (same b,h -> same K/V
// stream; 33 tile-units per block => perfect balance, 512 blocks = exactly
// 2/CU capacity).  Register prefetch of next tile's K/V gathers overlaps
// compute (T14).  64 q-rows per item, 4 waves x 16 rows, KV tile 64.
// ---------------------------------------------------------------------------
__global__ __launch_bounds__(256, 2)
void attn3(const unsigned* __restrict__ Qp, const unsigned* __restrict__ Kp,
           const unsigned* __restrict__ Vtp, unsigned* __restrict__ Cp)
{
    const int S = 2048, D = 2048, KVD = 512, MT = 4096;

    __shared__ __align__(16) u16 Kh[64 * 128], Kl[64 * 128];   // [k][d], XOR-swizzled
    __shared__ __align__(16) u16 Vh[128 * 64], Vl[128 * 64];   // [d][k], XOR-swizzled
    __shared__ __align__(16) u16 Ps[4][16][72];                // per-wave P plane

    const int t = threadIdx.x, w = t >> 6, lane = t & 63;
    const int lr = lane & 15, quad = lane >> 4;
    const int h = blockIdx.y, b = blockIdx.z;
    const int kvh = h >> 2;

    const int qt0 = blockIdx.x;          // 0..15  (short item)
    const int qt1 = 31 - blockIdx.x;     // 16..31 (long item)
    const int nt0 = qt0 + 1, nt1 = qt1 + 1;
    const int total = nt0 + nt1;         // 33 for every block

    // staging maps
    const int kr = t >> 2, kq = t & 3;      // K: row 0..63, col-quarter
    const int vd = t >> 1, vh2 = t & 1;     // V^T: row (d) 0..127, col-half
    const unsigned* kg = Kp + (size_t)(b * S + kr) * KVD + kvh * 128 + kq * 32;
    const unsigned* vg = Vtp + (size_t)(kvh * 128 + vd) * MT + b * S + vh2 * 32;
    char* KhB = (char*)Kh; char* KlB = (char*)Kl;
    char* VhB = (char*)Vh; char* VlB = (char*)Vl;

    uint4 kv[8], vv[8];
#define ISSUE_KV(K0)                                                     \
    do {                                                                 \
        _Pragma("unroll")                                                \
        for (int u = 0; u < 8; u++) {                                    \
            kv[u] = *(const uint4*)(kg + (size_t)(K0) * KVD + u * 4);    \
            vv[u] = *(const uint4*)(vg + (K0) + u * 4);                  \
        }                                                                \
    } while (0)

    short8 qh[4], ql[4];
    f32x4 acc[8];
    float mreg[4], lreg[4];
    int q0 = 0, nt = nt0;

    ISSUE_KV(0);

    for (int it = 0; it < total; it++) {
        const int item = (it >= nt0) ? 1 : 0;
        const int kt = item ? (it - nt0) : it;
        if (kt == 0) {
            nt = item ? nt1 : nt0;
            q0 = (item ? qt1 : qt0) * 64;
            const unsigned* qs = Qp + (size_t)(b * S + q0 + w * 16 + lr) * D + h * 128;
#pragma unroll
            for (int kk = 0; kk < 4; kk++) {
                const uint4* p = (const uint4*)(qs + kk * 32 + quad * 8);
                upk8(p[0], p[1], qh[kk], ql[kk]);
            }
#pragma unroll
            for (int dt = 0; dt < 8; dt++) acc[dt] = (f32x4){0.f, 0.f, 0.f, 0.f};
#pragma unroll
            for (int r = 0; r < 4; r++) { mreg[r] = -1e30f; lreg[r] = 0.f; }
        }
        const int k0 = kt * 64;

        __syncthreads();
        // unpack prefetched regs -> swizzled LDS planes
#pragma unroll
        for (int u2 = 0; u2 < 4; u2++) {
            short8 hh, ll;
            upk8(kv[2 * u2], kv[2 * u2 + 1], hh, ll);
            const int ko = (kr * 256 + kq * 64 + u2 * 16) ^ ((kr & 7) << 4);
            *(short8*)(KhB + ko) = hh;
            *(short8*)(KlB + ko) = ll;
            upk8(vv[2 * u2], vv[2 * u2 + 1], hh, ll);
            const int vo = (vd * 128 + vh2 * 64 + u2 * 16) ^ ((vd & 7) << 4);
            *(short8*)(VhB + vo) = hh;
            *(short8*)(VlB + vo) = ll;
        }
        __syncthreads();

        // issue next tile's gathers now; latency hides under compute below
        if (it + 1 < total) {
            const int nk0 = (it + 1 >= nt0) ? (it + 1 - nt0) * 64 : (it + 1) * 64;
            ISSUE_KV(nk0);
        }

        // S = Q*K^T  (3-product split)
        f32x4 sacc[4];
#pragma unroll
        for (int ct = 0; ct < 4; ct++) sacc[ct] = (f32x4){0.f, 0.f, 0.f, 0.f};
#pragma unroll
        for (int ks = 0; ks < 4; ks++) {
            short8 kbh[4], kbl[4];
#pragma unroll
            for (int ct = 0; ct < 4; ct++) {
                const int row = ct * 16 + lr;
                const int off = (row * 256 + ks * 64 + quad * 16) ^ ((row & 7) << 4);
                kbh[ct] = *(const short8*)(KhB + off);
                kbl[ct] = *(const short8*)(KlB + off);
            }
            __builtin_amdgcn_s_setprio(1);
#pragma unroll
            for (int ct = 0; ct < 4; ct++) {
                sacc[ct] = __builtin_amdgcn_mfma_f32_16x16x32_bf16(ql[ks], kbh[ct], sacc[ct], 0, 0, 0);
                sacc[ct] = __builtin_amdgcn_mfma_f32_16x16x32_bf16(qh[ks], kbl[ct], sacc[ct], 0, 0, 0);
                sacc[ct] = __builtin_amdgcn_mfma_f32_16x16x32_bf16(qh[ks], kbh[ct], sacc[ct], 0, 0, 0);
            }
            __builtin_amdgcn_s_setprio(0);
        }

        // online softmax; C-layout: row = quad*4+r, col = ct*16+lr
        const bool diag = (kt == nt - 1);
        float p[4][4];
#pragma unroll
        for (int r = 0; r < 4; r++) {
            const int qg = q0 + w * 16 + quad * 4 + r;
            float s0 = sacc[0][r], s1 = sacc[1][r], s2 = sacc[2][r], s3 = sacc[3][r];
            if (diag) {
                if (k0 +  0 + lr > qg) s0 = -1e30f;
                if (k0 + 16 + lr > qg) s1 = -1e30f;
                if (k0 + 32 + lr > qg) s2 = -1e30f;
                if (k0 + 48 + lr > qg) s3 = -1e30f;
            }
            float mt = fmaxf(fmaxf(s0, s1), fmaxf(s2, s3));
#pragma unroll
            for (int off = 1; off < 16; off <<= 1) mt = fmaxf(mt, __shfl_xor(mt, off));
            const float mnew  = fmaxf(mreg[r], mt);
            const float alpha = __expf(mreg[r] - mnew);
            p[r][0] = (s0 <= -1e29f) ? 0.f : __expf(s0 - mnew);
            p[r][1] = (s1 <= -1e29f) ? 0.f : __expf(s1 - mnew);
            p[r][2] = (s2 <= -1e29f) ? 0.f : __expf(s2 - mnew);
            p[r][3] = (s3 <= -1e29f) ? 0.f : __expf(s3 - mnew);
            float ps = p[r][0] + p[r][1] + p[r][2] + p[r][3];
#pragma unroll
            for (int off = 1; off < 16; off <<= 1) ps += __shfl_xor(ps, off);
            lreg[r] = lreg[r] * alpha + ps;
            mreg[r] = mnew;
#pragma unroll
            for (int dt = 0; dt < 8; dt++) acc[dt][r] *= alpha;
        }

        // ---- PV pass 1: P_hi * (V_hi + V_lo) ----
#pragma unroll
        for (int r = 0; r < 4; r++)
#pragma unroll
            for (int ct = 0; ct < 4; ct++)
                Ps[w][quad * 4 + r][ct * 16 + lr] = (u16)(__float_as_uint(p[r][ct]) >> 16);
#pragma unroll
        for (int ks2 = 0; ks2 < 2; ks2++) {
            const short8 pa = *(const short8*)((const char*)&Ps[w][lr][0] + ks2 * 64 + quad * 16);
            __builtin_amdgcn_s_setprio(1);
#pragma unroll
            for (int dt = 0; dt < 8; dt++) {
                const int vrow = dt * 16 + lr;
                const int off = (vrow * 128 + ks2 * 64 + quad * 16) ^ ((vrow & 7) << 4);
                const short8 vbh = *(const short8*)(VhB + off);
                const short8 vbl = *(const short8*)(VlB + off);
                acc[dt] = __builtin_amdgcn_mfma_f32_16x16x32_bf16(pa, vbh, acc[dt], 0, 0, 0);
                acc[dt] = __builtin_amdgcn_mfma_f32_16x16x32_bf16(pa, vbl, acc[dt], 0, 0, 0);
            }
            __builtin_amdgcn_s_setprio(0);
        }
        // ---- PV pass 2: P_lo * V_hi ----
#pragma unroll
        for (int r = 0; r < 4; r++)
#pragma unroll
            for (int ct = 0; ct < 4; ct++) {
                const unsigned ub = __float_as_uint(p[r][ct]);
                const unsigned uh = ub & 0xFFFF0000u;
                const float rr = p[r][ct] - __uint_as_float(uh);
                Ps[w][quad * 4 + r][ct * 16 + lr] = (u16)(__float_as_uint(rr) >> 16);
            }
#pragma unroll
        for (int ks2 = 0; ks2 < 2; ks2++) {
            const short8 pa = *(const short8*)((const char*)&Ps[w][lr][0] + ks2 * 64 + quad * 16);
            __builtin_amdgcn_s_setprio(1);
#pragma unroll
            for (int dt = 0; dt < 8; dt++) {
                const int vrow = dt * 16 + lr;
                const int off = (vrow * 128 + ks2 * 64 + quad * 16) ^ ((vrow & 7) << 4);
                const short8 vbh = *(const short8*)(VhB + off);
                acc[dt] = __builtin_amdgcn_mfma_f32_16x16x32_bf16(pa, vbh, acc[dt], 0, 0, 0);
            }
            __builtin_amdgcn_s_setprio(0);
        }

        // epilogue for the finished item
        if (kt == nt - 1) {
#pragma unroll
            for (int r = 0; r < 4; r++) {
                const float inv = 1.0f / lreg[r];
                unsigned* dst = Cp + (size_t)(b * S + q0 + w * 16 + quad * 4 + r) * D + h * 128 + lr;
#pragma unroll
                for (int dt = 0; dt < 8; dt++)
                    dst[dt * 16] = packf(acc[dt][r] * inv);
            }
        }
    }
#undef ISSUE_KV
}

// ---------------------------------------------------------------------------
extern "C" void kernel_launch(void* const* d_in, const int* in_sizes, int n_in,
                              void* d_out, int out_size, void* d_ws, size_t ws_size,
                              hipStream_t stream)
{
    const void* x  = d_in[0];
    const void* Wq = d_in[1];
    const void* bq = d_in[2];
    const void* Wk = d_in[3];
    const void* bk = d_in[4];
    const void* Wv = d_in[5];
    const void* bv = d_in[6];
    const void* Wo = d_in[7];
    const void* bo = d_in[8];
    const void* qg = d_in[9];

    const int B = 2, S = 2048, D = 2048, H = 16, KVH = 4, KVD = 512;
    const int M = B * S;   // 4096

    // packed hi|lo u32 tensors — footprint identical to the proven layout.
    unsigned* Qp  = (unsigned*)d_ws;              // [M][D]
    unsigned* Kp  = Qp + (size_t)M * D;           // [M][KVD]
    unsigned* Vtp = Kp + (size_t)M * KVD;         // [KVD][M]  (V^T)
    unsigned* Cp  = Vtp + (size_t)KVD * M;        // [M][D]
    int* flag = (int*)(Cp + (size_t)M * D);

    detect_dtype<<<1, 256, 0, stream>>>((const unsigned short*)x, 16384, flag);

    // Q = x*Wq^T + bq -> packed (pre-norm)
    gemm3<0, 1, 0><<<dim3(D / 128, M / 128), 256, 32768, stream>>>(
        x, Wq, bq, Qp, M, D, D, flag);
    // K = x*Wk^T + bk -> packed ; V^T = Wv*x^T + bv (row bias) -> packed
    gemm_kv<<<dim3(8, 32), 256, 32768, stream>>>(x, Wk, bk, Kp, Wv, bv, Vtp, flag);

    // RMSnorm + RoPE in-place (scale*gain folded into Q)
    norm_rope_pk<<<M * H, 64, 0, stream>>>(Qp, qg, H, 0.08838834764831845f, flag);
    norm_rope_pk<<<M * KVH, 64, 0, stream>>>(Kp, nullptr, KVH, 1.0f, flag);

    attn3<<<dim3(16, H, B), 256, 0, stream>>>(Qp, Kp, Vtp, Cp);

    // out = ctx*Wo^T + bo -> d_out (dtype follows input)
    gemm3<1, 2, 0><<<dim3(D / 128, M / 128), 256, 32768, stream>>>(
        Cp, Wo, bo, d_out, M, D, D, flag);
}